// Round 2
// baseline (269.064 us; speedup 1.0000x reference)
//
#include <hip/hip_runtime.h>

#define NPTS 65536
#define BATCH 2
#define CCH 128
#define HIDC 64
#define LDA 136   // aggT row stride in bf16 elems (128 + 8 pad -> 2-way LDS aliasing, free)
#define ZLD 72    // z staging row stride

typedef unsigned short u16;
typedef __bf16 bf16_t;
typedef bf16_t bf16x8 __attribute__((ext_vector_type(8)));
typedef float f32x4 __attribute__((ext_vector_type(4)));

__device__ __forceinline__ u16 f2bf(float f){
  union { float f; unsigned u; } v; v.f = f;
  unsigned r = v.u + 0x7FFFu + ((v.u >> 16) & 1u);
  return (u16)(r >> 16);
}
__device__ __forceinline__ float bf2f(u16 u){
  union { unsigned u; float f; } v; v.u = ((unsigned)u) << 16; return v.f;
}
__device__ __forceinline__ float sigmoidf_(float v){ return 1.f/(1.f+__expf(-v)); }
__device__ __forceinline__ float tanhf_(float v){
  v = fminf(10.f, fmaxf(-10.f, v));
  float e = __expf(2.f*v);
  return (e-1.f)/(e+1.f);
}

// Convert the three 64x128 fp32 out-projection matrices to bf16 in ws.
__global__ __launch_bounds__(256) void kprep(const float* __restrict__ wz,
    const float* __restrict__ wr, const float* __restrict__ wq, u16* __restrict__ o){
  int i = blockIdx.x*256 + threadIdx.x;          // 0..24575
  const float* s = (i < 8192) ? wz : ((i < 16384) ? wr : wq);
  o[i] = f2bf(s[i & 8191]);
}

// Pack hxT[b][n][0..127] = concat(h,x) as bf16 rows; also fill rhxT upper half (=x).
__global__ __launch_bounds__(256) void k_pack(const float* __restrict__ h,
    const float* __restrict__ x, u16* __restrict__ hxT, u16* __restrict__ rhxT){
  int pn = blockIdx.x*256 + threadIdx.x;         // == b*N + n, 0..131071
  int b = pn >> 16;
  size_t fb = (size_t)b*HIDC*NPTS + (pn & 65535);
  size_t ob = (size_t)pn * CCH;
  u16 tmp[8];
  for (int c8 = 0; c8 < 8; ++c8){
    #pragma unroll
    for (int i = 0; i < 8; ++i) tmp[i] = f2bf(h[fb + (size_t)(c8*8+i)*NPTS]);
    uint4 v; __builtin_memcpy(&v, tmp, 16);
    *(uint4*)(hxT + ob + c8*8) = v;
  }
  for (int c8 = 0; c8 < 8; ++c8){
    #pragma unroll
    for (int i = 0; i < 8; ++i) tmp[i] = f2bf(x[fb + (size_t)(c8*8+i)*NPTS]);
    uint4 v; __builtin_memcpy(&v, tmp, 16);
    *(uint4*)(hxT + ob + 64 + c8*8) = v;
    *(uint4*)(rhxT + ob + 64 + c8*8) = v;
  }
}

// z and r gates: shared neighbor gathers of hxT, depthwise agg -> LDS, MFMA out-proj,
// epilogue writes z (bf16) and rhxT lower half (= r*h) via LDS transpose.
__global__ __launch_bounds__(256) void k_zr(
    const float* __restrict__ xyz, const float* __restrict__ h,
    const int* __restrict__ knn,
    const float* __restrict__ wz_pos, const float* __restrict__ bz_pos,
    const float* __restrict__ bz_out,
    const float* __restrict__ wr_pos, const float* __restrict__ br_pos,
    const float* __restrict__ br_out,
    const u16* __restrict__ wzb, const u16* __restrict__ wrb,
    const u16* __restrict__ hxT, u16* __restrict__ rhxT, u16* __restrict__ z_ws)
{
  __shared__ __align__(16) u16 aggzT[64*LDA];
  __shared__ __align__(16) u16 aggrT[64*LDA];
  __shared__ __align__(16) u16 zst[64*ZLD];
  __shared__ float4 relk[256];
  __shared__ int jlds[256];
  __shared__ float4 wpz[128];
  __shared__ float4 wpr[128];

  int tid = threadIdx.x; int lane = tid & 63; int wv = tid >> 6;
  int bid = blockIdx.x; int b = bid >> 10; int n0 = (bid & 1023) << 6;
  size_t bN = (size_t)b * NPTS;

  { // preload idx + rel: tid = p*4 + k
    int p = tid >> 2, k = tid & 3;
    int j = knn[((bN + n0 + p) << 2) + k];
    jlds[tid] = j;
    const float* xb = xyz + (size_t)b*3*NPTS;
    float cx = xb[n0+p], cy = xb[NPTS + n0+p], cz = xb[2*NPTS + n0+p];
    relk[tid] = make_float4(xb[j]-cx, xb[NPTS+j]-cy, xb[2*NPTS+j]-cz, 0.f);
  }
  if (tid < 128){
    wpz[tid] = make_float4(wz_pos[tid*3], wz_pos[tid*3+1], wz_pos[tid*3+2], bz_pos[tid]);
  } else {
    int c = tid - 128;
    wpr[c] = make_float4(wr_pos[c*3], wr_pos[c*3+1], wr_pos[c*3+2], br_pos[c]);
  }
  __syncthreads();

  // stage 1: gather + depthwise aggregate (both gates share the gathers)
  const u16* hxTb = hxT + (bN << 7);
  for (int i = 0; i < 32; ++i){
    int t = (i << 2) | wv;                  // 0..127 task id
    int p = t >> 1; int c = ((t & 1) << 6) | lane;
    float4 wz4 = wpz[c], wr4 = wpr[c];
    float az = 0.f, ar = 0.f;
    #pragma unroll
    for (int k = 0; k < 4; ++k){
      int j = jlds[(p << 2) | k];
      float g = bf2f(hxTb[((size_t)j << 7) | c]);
      float4 r = relk[(p << 2) | k];
      az += (wz4.w + wz4.x*r.x + wz4.y*r.y + wz4.z*r.z) * g;
      ar += (wr4.w + wr4.x*r.x + wr4.y*r.y + wr4.z*r.z) * g;
    }
    aggzT[p*LDA + c] = f2bf(az);
    aggrT[p*LDA + c] = f2bf(ar);
  }
  __syncthreads();

  // stage 2: out-projection via MFMA. C[o,p] = W[o,c] @ agg[c,p]
  int l15 = lane & 15, quad = lane >> 4;
  bf16x8 Az[4], Ar[4];
  #pragma unroll
  for (int s = 0; s < 4; ++s){
    Az[s] = *(const bf16x8*)(wzb + ((wv*16 + l15)*128 + s*32 + quad*8));
    Ar[s] = *(const bf16x8*)(wrb + ((wv*16 + l15)*128 + s*32 + quad*8));
  }
  f32x4 zero4 = {0.f,0.f,0.f,0.f};
  f32x4 accz[4], accr[4];
  #pragma unroll
  for (int nt = 0; nt < 4; ++nt){ accz[nt] = zero4; accr[nt] = zero4; }
  #pragma unroll
  for (int nt = 0; nt < 4; ++nt){
    #pragma unroll
    for (int s = 0; s < 4; ++s){
      bf16x8 bz = *(const bf16x8*)(aggzT + ((nt*16 + l15)*LDA + s*32 + quad*8));
      accz[nt] = __builtin_amdgcn_mfma_f32_16x16x32_bf16(Az[s], bz, accz[nt], 0, 0, 0);
    }
    #pragma unroll
    for (int s = 0; s < 4; ++s){
      bf16x8 br = *(const bf16x8*)(aggrT + ((nt*16 + l15)*LDA + s*32 + quad*8));
      accr[nt] = __builtin_amdgcn_mfma_f32_16x16x32_bf16(Ar[s], br, accr[nt], 0, 0, 0);
    }
  }
  __syncthreads();   // all MFMA reads of aggT done before reuse

  // epilogue: z = sigmoid(...), rh = sigmoid(...)*h, staged to LDS for coalesced write
  #pragma unroll
  for (int nt = 0; nt < 4; ++nt){
    #pragma unroll
    for (int reg = 0; reg < 4; ++reg){
      int o = (wv << 4) | (quad << 2) | reg;   // C/D layout: row = quad*4+reg
      int p = (nt << 4) | l15;                 // col = lane&15
      float zf = sigmoidf_(accz[nt][reg] + bz_out[o]);
      float rf = sigmoidf_(accr[nt][reg] + br_out[o]);
      float hv = h[(size_t)(b*HIDC + o)*NPTS + n0 + p];
      zst[o*ZLD + p] = f2bf(zf);
      aggzT[p*LDA + o] = f2bf(rf * hv);        // reuse aggzT as [p][c] staging
    }
  }
  __syncthreads();

  // coalesced global writes: rhxT lower half (64 p x 64 c) = 512 uint4
  for (int t = tid; t < 512; t += 256){
    int p = t >> 3, ch = (t & 7) << 3;
    uint4 v = *(const uint4*)(aggzT + p*LDA + ch);
    *(uint4*)(rhxT + ((bN + n0 + p) << 7) + ch) = v;
  }
  // z staging: 64 o-rows x 64 p-cols = 512 uint4  (R1 fix: was 256 writes w/ wrong stride)
  for (int t = tid; t < 512; t += 256){
    int o = t >> 3, ch = (t & 7) << 3;
    uint4 v = *(const uint4*)(zst + o*ZLD + ch);
    *(uint4*)(z_ws + (size_t)(b*HIDC + o)*NPTS + n0 + ch) = v;
  }
}

// q gate + final combine: gathers rhxT, MFMA out-proj, out = (1-z)*h + z*q
__global__ __launch_bounds__(256) void k_q(
    const float* __restrict__ xyz, const float* __restrict__ h,
    const int* __restrict__ knn,
    const float* __restrict__ wq_pos, const float* __restrict__ bq_pos,
    const float* __restrict__ bq_out,
    const u16* __restrict__ wqb, const u16* __restrict__ rhxT,
    const u16* __restrict__ z_ws, float* __restrict__ out)
{
  __shared__ __align__(16) u16 aggT[64*LDA];
  __shared__ float4 relk[256];
  __shared__ int jlds[256];
  __shared__ float4 wpq[128];

  int tid = threadIdx.x; int lane = tid & 63; int wv = tid >> 6;
  int bid = blockIdx.x; int b = bid >> 10; int n0 = (bid & 1023) << 6;
  size_t bN = (size_t)b * NPTS;

  {
    int p = tid >> 2, k = tid & 3;
    int j = knn[((bN + n0 + p) << 2) + k];
    jlds[tid] = j;
    const float* xb = xyz + (size_t)b*3*NPTS;
    float cx = xb[n0+p], cy = xb[NPTS + n0+p], cz = xb[2*NPTS + n0+p];
    relk[tid] = make_float4(xb[j]-cx, xb[NPTS+j]-cy, xb[2*NPTS+j]-cz, 0.f);
  }
  if (tid < 128){
    wpq[tid] = make_float4(wq_pos[tid*3], wq_pos[tid*3+1], wq_pos[tid*3+2], bq_pos[tid]);
  }
  __syncthreads();

  const u16* rhxTb = rhxT + (bN << 7);
  for (int i = 0; i < 32; ++i){
    int t = (i << 2) | wv;
    int p = t >> 1; int c = ((t & 1) << 6) | lane;
    float4 wq4 = wpq[c];
    float aq = 0.f;
    #pragma unroll
    for (int k = 0; k < 4; ++k){
      int j = jlds[(p << 2) | k];
      float g = bf2f(rhxTb[((size_t)j << 7) | c]);
      float4 r = relk[(p << 2) | k];
      aq += (wq4.w + wq4.x*r.x + wq4.y*r.y + wq4.z*r.z) * g;
    }
    aggT[p*LDA + c] = f2bf(aq);
  }
  __syncthreads();

  int l15 = lane & 15, quad = lane >> 4;
  bf16x8 Aq[4];
  #pragma unroll
  for (int s = 0; s < 4; ++s)
    Aq[s] = *(const bf16x8*)(wqb + ((wv*16 + l15)*128 + s*32 + quad*8));
  f32x4 zero4 = {0.f,0.f,0.f,0.f};
  f32x4 acc[4];
  #pragma unroll
  for (int nt = 0; nt < 4; ++nt) acc[nt] = zero4;
  #pragma unroll
  for (int nt = 0; nt < 4; ++nt){
    #pragma unroll
    for (int s = 0; s < 4; ++s){
      bf16x8 bq = *(const bf16x8*)(aggT + ((nt*16 + l15)*LDA + s*32 + quad*8));
      acc[nt] = __builtin_amdgcn_mfma_f32_16x16x32_bf16(Aq[s], bq, acc[nt], 0, 0, 0);
    }
  }

  #pragma unroll
  for (int nt = 0; nt < 4; ++nt){
    #pragma unroll
    for (int reg = 0; reg < 4; ++reg){
      int o = (wv << 4) | (quad << 2) | reg;
      int p = (nt << 4) | l15;
      size_t idx = (size_t)(b*HIDC + o)*NPTS + n0 + p;
      float qf = tanhf_(acc[nt][reg] + bq_out[o]);
      float zf = bf2f(z_ws[idx]);
      float hv = h[idx];
      out[idx] = (1.f - zf)*hv + zf*qf;
    }
  }
}

extern "C" void kernel_launch(void* const* d_in, const int* in_sizes, int n_in,
                              void* d_out, int out_size, void* d_ws, size_t ws_size,
                              hipStream_t stream){
  const float* xyz    = (const float*)d_in[0];
  const float* h      = (const float*)d_in[1];
  const float* x      = (const float*)d_in[2];
  const int*   knn    = (const int*)d_in[3];
  const float* wz_pos = (const float*)d_in[4];
  const float* bz_pos = (const float*)d_in[5];
  const float* wz_out = (const float*)d_in[6];
  const float* bz_out = (const float*)d_in[7];
  const float* wr_pos = (const float*)d_in[8];
  const float* br_pos = (const float*)d_in[9];
  const float* wr_out = (const float*)d_in[10];
  const float* br_out = (const float*)d_in[11];
  const float* wq_pos = (const float*)d_in[12];
  const float* bq_pos = (const float*)d_in[13];
  const float* wq_out = (const float*)d_in[14];
  const float* bq_out = (const float*)d_in[15];
  float* out = (float*)d_out;

  // ws layout (bf16/u16 elems): hxT[2*65536*128] | rhxT[same] | z[2*64*65536] | w_bf16[3*8192]
  u16* ws   = (u16*)d_ws;
  u16* hxT  = ws;
  u16* rhxT = hxT + (size_t)BATCH*NPTS*CCH;
  u16* z_ws = rhxT + (size_t)BATCH*NPTS*CCH;
  u16* wbf  = z_ws + (size_t)BATCH*HIDC*NPTS;

  kprep<<<96, 256, 0, stream>>>(wz_out, wr_out, wq_out, wbf);
  k_pack<<<512, 256, 0, stream>>>(h, x, hxT, rhxT);
  k_zr<<<2048, 256, 0, stream>>>(xyz, h, knn, wz_pos, bz_pos, bz_out,
      wr_pos, br_pos, br_out, wbf, wbf + 8192, hxT, rhxT, z_ws);
  k_q<<<2048, 256, 0, stream>>>(xyz, h, knn, wq_pos, bq_pos, bq_out,
      wbf + 16384, rhxT, z_ws, out);
}

// Round 4
// 234.931 us; speedup vs baseline: 1.1453x; 1.1453x over previous
//
#include <hip/hip_runtime.h>

#define NPTS 65536
#define BATCH 2
#define CCH 128
#define HIDC 64
#define PPB 32        // points per block in gather kernels
#define LDB 520       // bext row stride (u16): 512 + 8 pad -> 2-way LDS aliasing only
#define PLD 136       // k_pack tile row stride (u16)

typedef unsigned short u16;
typedef unsigned int u32;
typedef __bf16 bf16_t;
typedef bf16_t bf16x8 __attribute__((ext_vector_type(8)));
typedef float f32x4 __attribute__((ext_vector_type(4)));

__device__ __forceinline__ u16 f2bf(float f){
  union { float f; unsigned u; } v; v.f = f;
  unsigned r = v.u + 0x7FFFu + ((v.u >> 16) & 1u);
  return (u16)(r >> 16);
}
__device__ __forceinline__ float bf2f(u16 u){
  union { unsigned u; float f; } v; v.u = ((unsigned)u) << 16; return v.f;
}
// pack two floats as bf16 pair: low=a, high=b
__device__ __forceinline__ u32 pkrn(float a, float b){
  union { float f; u32 u; } ua, ub; ua.f = a; ub.f = b;
  return ((ua.u + 0x8000u) >> 16) | ((ub.u + 0x8000u) & 0xffff0000u);
}
__device__ __forceinline__ float sigmoidf_(float v){ return 1.f/(1.f+__expf(-v)); }
__device__ __forceinline__ float tanhf_(float v){
  v = fminf(10.f, fmaxf(-10.f, v));
  float e = __expf(2.f*v);
  return (e-1.f)/(e+1.f);
}

// Build the moment-mixed A matrices (bf16) for the 3 gates, K=512, in the
// permuted fragment-friendly layout: A[((g*16+s)*4+quad)*64+o][t8].
// phys_k = s*32+quad*8+t;  j=pk>>7, chunk=(pk>>3)&15, tt=pk&7;
// orig = chunk*32+j*8+tt;  c=orig>>2, m=orig&3;  coef = m? w_pos[c][m-1] : b_pos[c]
__global__ __launch_bounds__(256) void kprep(
    const float* __restrict__ wz, const float* __restrict__ wzp, const float* __restrict__ bzp,
    const float* __restrict__ wr, const float* __restrict__ wrp, const float* __restrict__ brp,
    const float* __restrict__ wq, const float* __restrict__ wqp, const float* __restrict__ bqp,
    u16* __restrict__ A){
  int idx = blockIdx.x*256 + threadIdx.x;          // 0..98303
  int t = idx & 7, o = (idx>>3)&63, quad = (idx>>9)&3, s = (idx>>11)&15, g = idx>>15;
  int pk = s*32 + quad*8 + t;
  int j = pk>>7, chunk = (pk>>3)&15, tt = pk&7;
  int orig = chunk*32 + j*8 + tt;
  int c = orig>>2, m = orig&3;
  const float* W  = (g==0)? wz  : (g==1)? wr  : wq;
  const float* wp = (g==0)? wzp : (g==1)? wrp : wqp;
  const float* bp = (g==0)? bzp : (g==1)? brp : bqp;
  float coef = m ? wp[c*3 + m - 1] : bp[c];
  A[idx] = f2bf(W[o*CCH + c] * coef);
}

// Transpose h,x [B,64,N] fp32 -> hxT [B,N,128] bf16 rows; also x-half of rhxT.
__global__ __launch_bounds__(256) void k_pack(const float* __restrict__ h,
    const float* __restrict__ x, u16* __restrict__ hxT, u16* __restrict__ rhxT){
  __shared__ __align__(16) u16 tile[64*PLD];
  int tid = threadIdx.x;
  int b = blockIdx.x >> 10, n0 = (blockIdx.x & 1023) << 6;
  #pragma unroll
  for (int i = 0; i < 8; ++i){
    int cc = (tid>>4) + i*16;                      // 0..127
    int nn = (tid & 15)*4;
    const float* src = (cc < HIDC)
        ? (h + (((size_t)(b*HIDC + cc))<<16) + n0 + nn)
        : (x + (((size_t)(b*HIDC + cc - HIDC))<<16) + n0 + nn);
    float4 v = *(const float4*)src;
    tile[(nn+0)*PLD + cc] = f2bf(v.x);
    tile[(nn+1)*PLD + cc] = f2bf(v.y);
    tile[(nn+2)*PLD + cc] = f2bf(v.z);
    tile[(nn+3)*PLD + cc] = f2bf(v.w);
  }
  __syncthreads();
  #pragma unroll
  for (int i = 0; i < 4; ++i){
    int tsk = tid + (i<<8);                        // 0..1023: 64 n x 16 chunks
    int n = tsk>>4, ch = (tsk&15)*8;
    uint4 v = *(const uint4*)(tile + n*PLD + ch);
    *(uint4*)(hxT + (((size_t)(b<<16) + n0 + n)<<7) + ch) = v;
  }
  #pragma unroll
  for (int i = 0; i < 2; ++i){
    int tsk = tid + (i<<8);                        // 0..511: 64 n x 8 chunks (upper half)
    int n = tsk>>3, ch = HIDC + (tsk&7)*8;
    uint4 v = *(const uint4*)(tile + n*PLD + ch);
    *(uint4*)(rhxT + (((size_t)(b<<16) + n0 + n)<<7) + ch) = v;
  }
}

#define ACCUM(gv, rv) { \
  u32 dw_[4] = {gv.x, gv.y, gv.z, gv.w}; \
  _Pragma("unroll") \
  for (int q_ = 0; q_ < 4; ++q_){ \
    union { u32 u; float f; } lo_, hi_; \
    lo_.u = dw_[q_] << 16; hi_.u = dw_[q_] & 0xffff0000u; \
    m0[2*q_]   += lo_.f; mx[2*q_]   += rv.x*lo_.f; my[2*q_]   += rv.y*lo_.f; mz[2*q_]   += rv.z*lo_.f; \
    m0[2*q_+1] += hi_.f; mx[2*q_+1] += rv.x*hi_.f; my[2*q_+1] += rv.y*hi_.f; mz[2*q_+1] += rv.z*hi_.f; \
  } }

// z & r gates via moments: gather 4 neighbor rows (vector), accumulate
// G0,Gx,Gy,Gz into LDS B-matrix (K=512, permuted), 2 MFMA GEMMs, epilogue.
__global__ __launch_bounds__(256, 4) void k_zr(
    const float* __restrict__ xyz, const float* __restrict__ h,
    const int* __restrict__ knn,
    const float* __restrict__ bz_out, const float* __restrict__ br_out,
    const u16* __restrict__ Azr,    // gate0 at 0, gate1 at +32768
    const u16* __restrict__ hxT, u16* __restrict__ rhxT, u16* __restrict__ z_ws)
{
  __shared__ __align__(16) u16 bext[PPB*LDB];      // 33280 B
  __shared__ __align__(16) float4 relk[PPB*4];
  __shared__ __align__(16) int4 jlds[PPB];

  int tid = threadIdx.x; int lane = tid & 63; int wv = tid >> 6;
  int b = blockIdx.x >> 11, n0 = (blockIdx.x & 2047) << 5;
  size_t bN = (size_t)b * NPTS;

  if (tid < 128){
    int p = tid >> 2, k = tid & 3;
    int j = knn[((bN + n0 + p) << 2) + k];
    ((int*)jlds)[tid] = j;
    const float* xb = xyz + (size_t)b*3*NPTS;
    float cx = xb[n0+p], cy = xb[NPTS + n0+p], cz = xb[2*NPTS + n0+p];
    relk[tid] = make_float4(xb[j]-cx, xb[NPTS+j]-cy, xb[2*NPTS+j]-cz, 0.f);
  }
  __syncthreads();

  const u16* hxTb = hxT + (bN << 7);
  #pragma unroll
  for (int it = 0; it < 2; ++it){
    int task = tid + (it << 8);                    // 0..511
    int p = task >> 4, chunk = task & 15;
    int4 jj = jlds[p];
    uint4 g0 = *(const uint4*)(hxTb + (((size_t)jj.x)<<7) + chunk*8);
    uint4 g1 = *(const uint4*)(hxTb + (((size_t)jj.y)<<7) + chunk*8);
    uint4 g2 = *(const uint4*)(hxTb + (((size_t)jj.z)<<7) + chunk*8);
    uint4 g3 = *(const uint4*)(hxTb + (((size_t)jj.w)<<7) + chunk*8);
    float4 r0 = relk[p*4+0], r1 = relk[p*4+1], r2 = relk[p*4+2], r3 = relk[p*4+3];
    float m0[8] = {0,0,0,0,0,0,0,0}, mx[8] = {0,0,0,0,0,0,0,0};
    float my[8] = {0,0,0,0,0,0,0,0}, mz[8] = {0,0,0,0,0,0,0,0};
    ACCUM(g0, r0); ACCUM(g1, r1); ACCUM(g2, r2); ACCUM(g3, r3);
    u16* row = bext + p*LDB;
    #pragma unroll
    for (int j = 0; j < 4; ++j){
      int ca = 2*j, cb = 2*j+1;
      uint4 v;
      v.x = pkrn(m0[ca], mx[ca]); v.y = pkrn(my[ca], mz[ca]);
      v.z = pkrn(m0[cb], mx[cb]); v.w = pkrn(my[cb], mz[cb]);
      *(uint4*)(row + j*128 + chunk*8) = v;
    }
  }
  __syncthreads();

  // MFMA: out[o,p] over K=512, both gates share B-fragments
  int l15 = lane & 15, quad = lane >> 4;
  int orow = wv*16 + l15;
  f32x4 accz[2], accr[2];
  #pragma unroll
  for (int nt = 0; nt < 2; ++nt){ accz[nt] = (f32x4){0,0,0,0}; accr[nt] = (f32x4){0,0,0,0}; }
  #pragma unroll
  for (int s = 0; s < 16; ++s){
    bf16x8 az = *(const bf16x8*)(Azr + ((s*4 + quad)*64 + orow)*8);
    bf16x8 ar = *(const bf16x8*)(Azr + 32768 + ((s*4 + quad)*64 + orow)*8);
    #pragma unroll
    for (int nt = 0; nt < 2; ++nt){
      bf16x8 bb = *(const bf16x8*)(bext + (nt*16 + l15)*LDB + s*32 + quad*8);
      accz[nt] = __builtin_amdgcn_mfma_f32_16x16x32_bf16(az, bb, accz[nt], 0, 0, 0);
      accr[nt] = __builtin_amdgcn_mfma_f32_16x16x32_bf16(ar, bb, accr[nt], 0, 0, 0);
    }
  }
  __syncthreads();   // bext reads done; reuse as staging

  u16* zst  = bext;                 // [64 o][40]
  u16* rhst = bext + 64*40;         // [32 p][72]
  #pragma unroll
  for (int nt = 0; nt < 2; ++nt){
    #pragma unroll
    for (int reg = 0; reg < 4; ++reg){
      int o = wv*16 + quad*4 + reg;               // C/D: row = quad*4+reg
      int p = nt*16 + l15;                        // col = lane&15
      float zf = sigmoidf_(accz[nt][reg] + bz_out[o]);
      float rf = sigmoidf_(accr[nt][reg] + br_out[o]);
      float hv = h[(((size_t)(b*HIDC + o))<<16) + n0 + p];
      zst[o*40 + p] = f2bf(zf);
      rhst[p*72 + o] = f2bf(rf * hv);
    }
  }
  __syncthreads();

  { // rhxT lower half: 32 p x 64 ch = 256 uint4, one per thread
    int p = tid >> 3, ch = (tid & 7)*8;
    uint4 v = *(const uint4*)(rhst + p*72 + ch);
    *(uint4*)(rhxT + ((bN + n0 + p)<<7) + ch) = v;
  }
  { // z: 64 o x 32 p u16 = 256 uint4, one per thread (R3 fix: was 128 w/ gaps)
    int o = tid >> 2, pc = (tid & 3)*8;
    uint4 v = *(const uint4*)(zst + o*40 + pc);
    *(uint4*)(z_ws + (((size_t)(b*HIDC + o))<<16) + n0 + pc) = v;
  }
}

// q gate + final combine
__global__ __launch_bounds__(256, 4) void k_q(
    const float* __restrict__ xyz, const float* __restrict__ h,
    const int* __restrict__ knn,
    const float* __restrict__ bq_out,
    const u16* __restrict__ Aq,
    const u16* __restrict__ rhxT, const u16* __restrict__ z_ws,
    float* __restrict__ out)
{
  __shared__ __align__(16) u16 bext[PPB*LDB];
  __shared__ __align__(16) float4 relk[PPB*4];
  __shared__ __align__(16) int4 jlds[PPB];

  int tid = threadIdx.x; int lane = tid & 63; int wv = tid >> 6;
  int b = blockIdx.x >> 11, n0 = (blockIdx.x & 2047) << 5;
  size_t bN = (size_t)b * NPTS;

  if (tid < 128){
    int p = tid >> 2, k = tid & 3;
    int j = knn[((bN + n0 + p) << 2) + k];
    ((int*)jlds)[tid] = j;
    const float* xb = xyz + (size_t)b*3*NPTS;
    float cx = xb[n0+p], cy = xb[NPTS + n0+p], cz = xb[2*NPTS + n0+p];
    relk[tid] = make_float4(xb[j]-cx, xb[NPTS+j]-cy, xb[2*NPTS+j]-cz, 0.f);
  }
  __syncthreads();

  const u16* rhxTb = rhxT + (bN << 7);
  #pragma unroll
  for (int it = 0; it < 2; ++it){
    int task = tid + (it << 8);
    int p = task >> 4, chunk = task & 15;
    int4 jj = jlds[p];
    uint4 g0 = *(const uint4*)(rhxTb + (((size_t)jj.x)<<7) + chunk*8);
    uint4 g1 = *(const uint4*)(rhxTb + (((size_t)jj.y)<<7) + chunk*8);
    uint4 g2 = *(const uint4*)(rhxTb + (((size_t)jj.z)<<7) + chunk*8);
    uint4 g3 = *(const uint4*)(rhxTb + (((size_t)jj.w)<<7) + chunk*8);
    float4 r0 = relk[p*4+0], r1 = relk[p*4+1], r2 = relk[p*4+2], r3 = relk[p*4+3];
    float m0[8] = {0,0,0,0,0,0,0,0}, mx[8] = {0,0,0,0,0,0,0,0};
    float my[8] = {0,0,0,0,0,0,0,0}, mz[8] = {0,0,0,0,0,0,0,0};
    ACCUM(g0, r0); ACCUM(g1, r1); ACCUM(g2, r2); ACCUM(g3, r3);
    u16* row = bext + p*LDB;
    #pragma unroll
    for (int j = 0; j < 4; ++j){
      int ca = 2*j, cb = 2*j+1;
      uint4 v;
      v.x = pkrn(m0[ca], mx[ca]); v.y = pkrn(my[ca], mz[ca]);
      v.z = pkrn(m0[cb], mx[cb]); v.w = pkrn(my[cb], mz[cb]);
      *(uint4*)(row + j*128 + chunk*8) = v;
    }
  }
  __syncthreads();

  int l15 = lane & 15, quad = lane >> 4;
  int orow = wv*16 + l15;
  f32x4 acc[2];
  #pragma unroll
  for (int nt = 0; nt < 2; ++nt) acc[nt] = (f32x4){0,0,0,0};
  #pragma unroll
  for (int s = 0; s < 16; ++s){
    bf16x8 aq = *(const bf16x8*)(Aq + ((s*4 + quad)*64 + orow)*8);
    #pragma unroll
    for (int nt = 0; nt < 2; ++nt){
      bf16x8 bb = *(const bf16x8*)(bext + (nt*16 + l15)*LDB + s*32 + quad*8);
      acc[nt] = __builtin_amdgcn_mfma_f32_16x16x32_bf16(aq, bb, acc[nt], 0, 0, 0);
    }
  }

  #pragma unroll
  for (int nt = 0; nt < 2; ++nt){
    #pragma unroll
    for (int reg = 0; reg < 4; ++reg){
      int o = wv*16 + quad*4 + reg;
      int p = nt*16 + l15;
      size_t idx = (((size_t)(b*HIDC + o))<<16) + n0 + p;
      float qf = tanhf_(acc[nt][reg] + bq_out[o]);
      float zf = bf2f(z_ws[idx]);
      float hv = h[idx];
      out[idx] = (1.f - zf)*hv + zf*qf;
    }
  }
}

extern "C" void kernel_launch(void* const* d_in, const int* in_sizes, int n_in,
                              void* d_out, int out_size, void* d_ws, size_t ws_size,
                              hipStream_t stream){
  const float* xyz    = (const float*)d_in[0];
  const float* h      = (const float*)d_in[1];
  const float* x      = (const float*)d_in[2];
  const int*   knn    = (const int*)d_in[3];
  const float* wz_pos = (const float*)d_in[4];
  const float* bz_pos = (const float*)d_in[5];
  const float* wz_out = (const float*)d_in[6];
  const float* bz_out = (const float*)d_in[7];
  const float* wr_pos = (const float*)d_in[8];
  const float* br_pos = (const float*)d_in[9];
  const float* wr_out = (const float*)d_in[10];
  const float* br_out = (const float*)d_in[11];
  const float* wq_pos = (const float*)d_in[12];
  const float* bq_pos = (const float*)d_in[13];
  const float* wq_out = (const float*)d_in[14];
  const float* bq_out = (const float*)d_in[15];
  float* out = (float*)d_out;

  // ws (u16 elems): hxT[2*65536*128] | rhxT[same] | z[2*64*65536] | A[3*32768]
  u16* ws   = (u16*)d_ws;
  u16* hxT  = ws;
  u16* rhxT = hxT + (size_t)BATCH*NPTS*CCH;
  u16* z_ws = rhxT + (size_t)BATCH*NPTS*CCH;
  u16* A    = z_ws + (size_t)BATCH*HIDC*NPTS;

  kprep<<<384, 256, 0, stream>>>(wz_out, wz_pos, bz_pos, wr_out, wr_pos, br_pos,
                                 wq_out, wq_pos, bq_pos, A);
  k_pack<<<2048, 256, 0, stream>>>(h, x, hxT, rhxT);
  k_zr<<<4096, 256, 0, stream>>>(xyz, h, knn, bz_out, br_out, A, hxT, rhxT, z_ws);
  k_q<<<4096, 256, 0, stream>>>(xyz, h, knn, bq_out, A + 65536, rhxT, z_ws, out);
}

// Round 5
// 222.486 us; speedup vs baseline: 1.2094x; 1.0559x over previous
//
#include <hip/hip_runtime.h>

#define NPTS 65536
#define BATCH 2
#define CCH 128
#define HIDC 64
#define LDB 520      // k_zr bext row stride u16 (512+8 pad)
#define LDB2 264     // k_q bext row stride u16 (256+8 pad)
#define PLD 130      // k_pack tile row stride u16 (2 mod 4 -> 2-way banks on transpose writes)

typedef unsigned short u16;
typedef unsigned int u32;
typedef __bf16 bf16_t;
typedef bf16_t bf16x8 __attribute__((ext_vector_type(8)));
typedef float f32x4 __attribute__((ext_vector_type(4)));

__device__ __forceinline__ u16 f2bf(float f){
  union { float f; unsigned u; } v; v.f = f;
  unsigned r = v.u + 0x7FFFu + ((v.u >> 16) & 1u);
  return (u16)(r >> 16);
}
__device__ __forceinline__ float bf2f(u16 u){
  union { unsigned u; float f; } v; v.u = ((unsigned)u) << 16; return v.f;
}
__device__ __forceinline__ u32 pkrn(float a, float b){
  union { float f; u32 u; } ua, ub; ua.f = a; ub.f = b;
  return ((ua.u + 0x8000u) >> 16) | ((ub.u + 0x8000u) & 0xffff0000u);
}
__device__ __forceinline__ float sigmoidf_(float v){ return 1.f/(1.f+__expf(-v)); }
__device__ __forceinline__ float tanhf_(float v){
  v = fminf(10.f, fmaxf(-10.f, v));
  float e = __expf(2.f*v);
  return (e-1.f)/(e+1.f);
}

// A matrices (bf16), fragment-permuted. First 98304: Az|Ar|Aq at K=512
// (phys k = s*32+quad*8+t; j=pk>>7, chunk=(pk>>3)&15, tt=pk&7;
//  orig=chunk*32+j*8+tt; c=orig>>2, m=orig&3). Then 16384: Aqrh at K=256
// (k2=s*32+quad*8+t; j=k2>>6, chunk=(k2>>3)&7; c in [0,64)).
__global__ __launch_bounds__(256) void kprep(
    const float* __restrict__ wz, const float* __restrict__ wzp, const float* __restrict__ bzp,
    const float* __restrict__ wr, const float* __restrict__ wrp, const float* __restrict__ brp,
    const float* __restrict__ wq, const float* __restrict__ wqp, const float* __restrict__ bqp,
    u16* __restrict__ A){
  int idx = blockIdx.x*256 + threadIdx.x;          // 0..114687
  if (idx < 98304){
    int t = idx & 7, o = (idx>>3)&63, quad = (idx>>9)&3, s = (idx>>11)&15, g = idx>>15;
    int pk = s*32 + quad*8 + t;
    int j = pk>>7, chunk = (pk>>3)&15, tt = pk&7;
    int orig = chunk*32 + j*8 + tt;
    int c = orig>>2, m = orig&3;
    const float* W  = (g==0)? wz  : (g==1)? wr  : wq;
    const float* wp = (g==0)? wzp : (g==1)? wrp : wqp;
    const float* bp = (g==0)? bzp : (g==1)? brp : bqp;
    float coef = m ? wp[c*3 + m - 1] : bp[c];
    A[idx] = f2bf(W[o*CCH + c] * coef);
  } else {
    int i2 = idx - 98304;
    int t = i2 & 7, o = (i2>>3)&63, quad = (i2>>9)&3, s = (i2>>11)&7;
    int k2 = s*32 + quad*8 + t;
    int j = k2>>6, chunk = (k2>>3)&7, tt = k2&7;
    int orig = chunk*32 + j*8 + tt;
    int c = orig>>2, m = orig&3;                   // c in [0,64): rh channels
    float coef = m ? wqp[c*3 + m - 1] : bqp[c];
    A[idx] = f2bf(wq[o*CCH + c] * coef);
  }
}

// Transpose h,x [B,64,N] fp32 -> hxT [B,N,128] bf16 rows.
__global__ __launch_bounds__(256) void k_pack(const float* __restrict__ h,
    const float* __restrict__ x, u16* __restrict__ hxT){
  __shared__ __align__(16) u16 tile[64*PLD];
  int tid = threadIdx.x;
  int b = blockIdx.x >> 10, n0 = (blockIdx.x & 1023) << 6;
  #pragma unroll
  for (int i = 0; i < 8; ++i){
    int cc = (tid>>4) + i*16;                      // 0..127
    int nn = (tid & 15)*4;
    const float* src = (cc < HIDC)
        ? (h + (((size_t)(b*HIDC + cc))<<16) + n0 + nn)
        : (x + (((size_t)(b*HIDC + cc - HIDC))<<16) + n0 + nn);
    float4 v = *(const float4*)src;
    tile[(nn+0)*PLD + cc] = f2bf(v.x);
    tile[(nn+1)*PLD + cc] = f2bf(v.y);
    tile[(nn+2)*PLD + cc] = f2bf(v.z);
    tile[(nn+3)*PLD + cc] = f2bf(v.w);
  }
  __syncthreads();
  #pragma unroll
  for (int i = 0; i < 4; ++i){
    int tsk = tid + (i<<8);                        // 0..1023: 64 n x 16 chunks
    int n = tsk>>4, ch = (tsk&15)*8;
    uint4 v = *(const uint4*)(tile + n*PLD + ch);
    *(uint4*)(hxT + (((size_t)(b<<16) + n0 + n)<<7) + ch) = v;
  }
}

#define ACCUM(gv, rv) { \
  u32 dw_[4] = {gv.x, gv.y, gv.z, gv.w}; \
  _Pragma("unroll") \
  for (int q_ = 0; q_ < 4; ++q_){ \
    union { u32 u; float f; } lo_, hi_; \
    lo_.u = dw_[q_] << 16; hi_.u = dw_[q_] & 0xffff0000u; \
    m0[2*q_]   += lo_.f; mx[2*q_]   += rv.x*lo_.f; my[2*q_]   += rv.y*lo_.f; mz[2*q_]   += rv.z*lo_.f; \
    m0[2*q_+1] += hi_.f; mx[2*q_+1] += rv.x*hi_.f; my[2*q_+1] += rv.y*hi_.f; mz[2*q_+1] += rv.z*hi_.f; \
  } }

#define PACKROW(row, CHOFF, STRIDE) { \
  _Pragma("unroll") \
  for (int j_ = 0; j_ < 4; ++j_){ \
    int ca_ = 2*j_, cb_ = 2*j_+1; \
    uint4 v_; \
    v_.x = pkrn(m0[ca_], mx[ca_]); v_.y = pkrn(my[ca_], mz[ca_]); \
    v_.z = pkrn(m0[cb_], mx[cb_]); v_.w = pkrn(my[cb_], mz[cb_]); \
    *(uint4*)((row) + j_*(STRIDE) + (CHOFF)) = v_; \
  } }

// z & r gates + q-gate x-partial. 32 points/block.
__global__ __launch_bounds__(256, 4) void k_zr(
    const float* __restrict__ xyz, const float* __restrict__ h,
    const int* __restrict__ knn,
    const float* __restrict__ bz_out, const float* __restrict__ br_out,
    const u16* __restrict__ Azr,    // Az at 0, Ar at +32768, Aq at +65536
    const u16* __restrict__ hxT, u16* __restrict__ rhT,
    u16* __restrict__ z_ws, u16* __restrict__ qx_ws)
{
  __shared__ __align__(16) u16 bext[32*LDB];       // 33280 B
  __shared__ __align__(16) float4 relk[128];
  __shared__ __align__(16) int4 jlds[32];

  int tid = threadIdx.x; int lane = tid & 63; int wv = tid >> 6;
  int b = blockIdx.x >> 11, n0 = (blockIdx.x & 2047) << 5;
  size_t bN = (size_t)b * NPTS;

  if (tid < 128){
    int p = tid >> 2, k = tid & 3;
    int j = knn[((bN + n0 + p) << 2) + k];
    ((int*)jlds)[tid] = j;
    const float* xb = xyz + (size_t)b*3*NPTS;
    float cx = xb[n0+p], cy = xb[NPTS + n0+p], cz = xb[2*NPTS + n0+p];
    relk[tid] = make_float4(xb[j]-cx, xb[NPTS+j]-cy, xb[2*NPTS+j]-cz, 0.f);
  }
  __syncthreads();

  // gather: 2 tasks/thread, all 8 loads issued before any accumulation
  const u16* hxTb = hxT + (bN << 7);
  int pA = tid >> 4, chk = tid & 15;
  int pB = pA + 16;
  int4 jA = jlds[pA], jB = jlds[pB];
  const u16* cb = hxTb + chk*8;
  uint4 ga0 = *(const uint4*)(cb + (((size_t)jA.x)<<7));
  uint4 ga1 = *(const uint4*)(cb + (((size_t)jA.y)<<7));
  uint4 ga2 = *(const uint4*)(cb + (((size_t)jA.z)<<7));
  uint4 ga3 = *(const uint4*)(cb + (((size_t)jA.w)<<7));
  uint4 gb0 = *(const uint4*)(cb + (((size_t)jB.x)<<7));
  uint4 gb1 = *(const uint4*)(cb + (((size_t)jB.y)<<7));
  uint4 gb2 = *(const uint4*)(cb + (((size_t)jB.z)<<7));
  uint4 gb3 = *(const uint4*)(cb + (((size_t)jB.w)<<7));
  {
    float4 r0 = relk[pA*4+0], r1 = relk[pA*4+1], r2 = relk[pA*4+2], r3 = relk[pA*4+3];
    float m0[8] = {0,0,0,0,0,0,0,0}, mx[8] = {0,0,0,0,0,0,0,0};
    float my[8] = {0,0,0,0,0,0,0,0}, mz[8] = {0,0,0,0,0,0,0,0};
    ACCUM(ga0, r0); ACCUM(ga1, r1); ACCUM(ga2, r2); ACCUM(ga3, r3);
    PACKROW(bext + pA*LDB, chk*8, 128);
  }
  {
    float4 r0 = relk[pB*4+0], r1 = relk[pB*4+1], r2 = relk[pB*4+2], r3 = relk[pB*4+3];
    float m0[8] = {0,0,0,0,0,0,0,0}, mx[8] = {0,0,0,0,0,0,0,0};
    float my[8] = {0,0,0,0,0,0,0,0}, mz[8] = {0,0,0,0,0,0,0,0};
    ACCUM(gb0, r0); ACCUM(gb1, r1); ACCUM(gb2, r2); ACCUM(gb3, r3);
    PACKROW(bext + pB*LDB, chk*8, 128);
  }
  __syncthreads();

  // MFMA: z,r over K=512; q x-part over the s&2 slices (c>=64)
  int l15 = lane & 15, quad = lane >> 4;
  int orow = wv*16 + l15;
  f32x4 accz[2], accr[2], accq[2];
  #pragma unroll
  for (int nt = 0; nt < 2; ++nt){
    accz[nt] = (f32x4){0,0,0,0}; accr[nt] = (f32x4){0,0,0,0}; accq[nt] = (f32x4){0,0,0,0};
  }
  #pragma unroll
  for (int s = 0; s < 16; ++s){
    bf16x8 az = *(const bf16x8*)(Azr + ((s*4 + quad)*64 + orow)*8);
    bf16x8 ar = *(const bf16x8*)(Azr + 32768 + ((s*4 + quad)*64 + orow)*8);
    if (s & 2){
      bf16x8 aq = *(const bf16x8*)(Azr + 65536 + ((s*4 + quad)*64 + orow)*8);
      #pragma unroll
      for (int nt = 0; nt < 2; ++nt){
        bf16x8 bb = *(const bf16x8*)(bext + (nt*16 + l15)*LDB + s*32 + quad*8);
        accz[nt] = __builtin_amdgcn_mfma_f32_16x16x32_bf16(az, bb, accz[nt], 0, 0, 0);
        accr[nt] = __builtin_amdgcn_mfma_f32_16x16x32_bf16(ar, bb, accr[nt], 0, 0, 0);
        accq[nt] = __builtin_amdgcn_mfma_f32_16x16x32_bf16(aq, bb, accq[nt], 0, 0, 0);
      }
    } else {
      #pragma unroll
      for (int nt = 0; nt < 2; ++nt){
        bf16x8 bb = *(const bf16x8*)(bext + (nt*16 + l15)*LDB + s*32 + quad*8);
        accz[nt] = __builtin_amdgcn_mfma_f32_16x16x32_bf16(az, bb, accz[nt], 0, 0, 0);
        accr[nt] = __builtin_amdgcn_mfma_f32_16x16x32_bf16(ar, bb, accr[nt], 0, 0, 0);
      }
    }
  }
  __syncthreads();   // bext reads done; reuse as staging

  u16* zst  = bext;                 // [64 o][40]
  u16* rhst = bext + 2560;          // [32 p][72]
  u16* qxst = bext + 2560 + 2304;   // [64 o][40]
  #pragma unroll
  for (int nt = 0; nt < 2; ++nt){
    #pragma unroll
    for (int reg = 0; reg < 4; ++reg){
      int o = wv*16 + quad*4 + reg;               // C/D: row = quad*4+reg
      int p = nt*16 + l15;                        // col = lane&15
      float zf = sigmoidf_(accz[nt][reg] + bz_out[o]);
      float rf = sigmoidf_(accr[nt][reg] + br_out[o]);
      float hv = h[(((size_t)(b*HIDC + o))<<16) + n0 + p];
      zst[o*40 + p] = f2bf(zf);
      rhst[p*72 + o] = f2bf(rf * hv);
      qxst[o*40 + p] = f2bf(accq[nt][reg]);       // no bias (bq_out added in k_q)
    }
  }
  __syncthreads();

  { // rhT: 32 p x 64 ch = 256 uint4, one per thread
    int p = tid >> 3, ch = (tid & 7)*8;
    uint4 v = *(const uint4*)(rhst + p*72 + ch);
    *(uint4*)(rhT + ((bN + n0 + p)<<6) + ch) = v;
  }
  { // z: 64 o x 32 p = 256 uint4
    int o = tid >> 2, pc = (tid & 3)*8;
    uint4 v = *(const uint4*)(zst + o*40 + pc);
    *(uint4*)(z_ws + (((size_t)(b*HIDC + o))<<16) + n0 + pc) = v;
  }
  { // qx: 64 o x 32 p = 256 uint4
    int o = tid >> 2, pc = (tid & 3)*8;
    uint4 v = *(const uint4*)(qxst + o*40 + pc);
    *(uint4*)(qx_ws + (((size_t)(b*HIDC + o))<<16) + n0 + pc) = v;
  }
}

// q gate (rh half via gather, x half from qx_ws) + final combine. 64 points/block.
__global__ __launch_bounds__(256, 4) void k_q(
    const float* __restrict__ xyz, const float* __restrict__ h,
    const int* __restrict__ knn,
    const float* __restrict__ bq_out,
    const u16* __restrict__ Aqrh,
    const u16* __restrict__ rhT, const u16* __restrict__ z_ws,
    const u16* __restrict__ qx_ws, float* __restrict__ out)
{
  __shared__ __align__(16) u16 bext[64*LDB2];      // 33792 B
  __shared__ __align__(16) float4 relk[256];
  __shared__ __align__(16) int4 jlds[64];

  int tid = threadIdx.x; int lane = tid & 63; int wv = tid >> 6;
  int b = blockIdx.x >> 10, n0 = (blockIdx.x & 1023) << 6;
  size_t bN = (size_t)b * NPTS;

  {
    int p = tid >> 2, k = tid & 3;
    int j = knn[((bN + n0 + p) << 2) + k];
    ((int*)jlds)[tid] = j;
    const float* xb = xyz + (size_t)b*3*NPTS;
    float cx = xb[n0+p], cy = xb[NPTS + n0+p], cz = xb[2*NPTS + n0+p];
    relk[tid] = make_float4(xb[j]-cx, xb[NPTS+j]-cy, xb[2*NPTS+j]-cz, 0.f);
  }
  __syncthreads();

  // gather rh rows (64 ch = 128 B): 2 tasks/thread, 8 loads in flight
  const u16* rhTb = rhT + (bN << 6);
  int pA = tid >> 3, chk = tid & 7;
  int pB = pA + 32;
  int4 jA = jlds[pA], jB = jlds[pB];
  const u16* cb = rhTb + chk*8;
  uint4 ga0 = *(const uint4*)(cb + (((size_t)jA.x)<<6));
  uint4 ga1 = *(const uint4*)(cb + (((size_t)jA.y)<<6));
  uint4 ga2 = *(const uint4*)(cb + (((size_t)jA.z)<<6));
  uint4 ga3 = *(const uint4*)(cb + (((size_t)jA.w)<<6));
  uint4 gb0 = *(const uint4*)(cb + (((size_t)jB.x)<<6));
  uint4 gb1 = *(const uint4*)(cb + (((size_t)jB.y)<<6));
  uint4 gb2 = *(const uint4*)(cb + (((size_t)jB.z)<<6));
  uint4 gb3 = *(const uint4*)(cb + (((size_t)jB.w)<<6));
  {
    float4 r0 = relk[pA*4+0], r1 = relk[pA*4+1], r2 = relk[pA*4+2], r3 = relk[pA*4+3];
    float m0[8] = {0,0,0,0,0,0,0,0}, mx[8] = {0,0,0,0,0,0,0,0};
    float my[8] = {0,0,0,0,0,0,0,0}, mz[8] = {0,0,0,0,0,0,0,0};
    ACCUM(ga0, r0); ACCUM(ga1, r1); ACCUM(ga2, r2); ACCUM(ga3, r3);
    PACKROW(bext + pA*LDB2, chk*8, 64);
  }
  {
    float4 r0 = relk[pB*4+0], r1 = relk[pB*4+1], r2 = relk[pB*4+2], r3 = relk[pB*4+3];
    float m0[8] = {0,0,0,0,0,0,0,0}, mx[8] = {0,0,0,0,0,0,0,0};
    float my[8] = {0,0,0,0,0,0,0,0}, mz[8] = {0,0,0,0,0,0,0,0};
    ACCUM(gb0, r0); ACCUM(gb1, r1); ACCUM(gb2, r2); ACCUM(gb3, r3);
    PACKROW(bext + pB*LDB2, chk*8, 64);
  }
  __syncthreads();

  int l15 = lane & 15, quad = lane >> 4;
  int orow = wv*16 + l15;
  f32x4 acc[4];
  #pragma unroll
  for (int nt = 0; nt < 4; ++nt) acc[nt] = (f32x4){0,0,0,0};
  #pragma unroll
  for (int s = 0; s < 8; ++s){
    bf16x8 aq = *(const bf16x8*)(Aqrh + ((s*4 + quad)*64 + orow)*8);
    #pragma unroll
    for (int nt = 0; nt < 4; ++nt){
      bf16x8 bb = *(const bf16x8*)(bext + (nt*16 + l15)*LDB2 + s*32 + quad*8);
      acc[nt] = __builtin_amdgcn_mfma_f32_16x16x32_bf16(aq, bb, acc[nt], 0, 0, 0);
    }
  }

  #pragma unroll
  for (int nt = 0; nt < 4; ++nt){
    #pragma unroll
    for (int reg = 0; reg < 4; ++reg){
      int o = wv*16 + quad*4 + reg;
      int p = nt*16 + l15;
      size_t idx = (((size_t)(b*HIDC + o))<<16) + n0 + p;
      float qpre = acc[nt][reg] + bq_out[o] + bf2f(qx_ws[idx]);
      float qf = tanhf_(qpre);
      float zf = bf2f(z_ws[idx]);
      float hv = h[idx];
      out[idx] = (1.f - zf)*hv + zf*qf;
    }
  }
}

extern "C" void kernel_launch(void* const* d_in, const int* in_sizes, int n_in,
                              void* d_out, int out_size, void* d_ws, size_t ws_size,
                              hipStream_t stream){
  const float* xyz    = (const float*)d_in[0];
  const float* h      = (const float*)d_in[1];
  const float* x      = (const float*)d_in[2];
  const int*   knn    = (const int*)d_in[3];
  const float* wz_pos = (const float*)d_in[4];
  const float* bz_pos = (const float*)d_in[5];
  const float* wz_out = (const float*)d_in[6];
  const float* bz_out = (const float*)d_in[7];
  const float* wr_pos = (const float*)d_in[8];
  const float* br_pos = (const float*)d_in[9];
  const float* wr_out = (const float*)d_in[10];
  const float* br_out = (const float*)d_in[11];
  const float* wq_pos = (const float*)d_in[12];
  const float* bq_pos = (const float*)d_in[13];
  const float* wq_out = (const float*)d_in[14];
  const float* bq_out = (const float*)d_in[15];
  float* out = (float*)d_out;

  // ws (u16): hxT[16777216] | rhT[8388608] | z[8388608] | qx[8388608] | A[114688]
  u16* ws    = (u16*)d_ws;
  u16* hxT   = ws;
  u16* rhT   = ws + 16777216;
  u16* z_ws  = ws + 25165824;
  u16* qx_ws = ws + 33554432;
  u16* A     = ws + 41943040;

  kprep<<<448, 256, 0, stream>>>(wz_out, wz_pos, bz_pos, wr_out, wr_pos, br_pos,
                                 wq_out, wq_pos, bq_pos, A);
  k_pack<<<2048, 256, 0, stream>>>(h, x, hxT);
  k_zr<<<4096, 256, 0, stream>>>(xyz, h, knn, bz_out, br_out, A, hxT, rhT, z_ws, qx_ws);
  k_q<<<2048, 256, 0, stream>>>(xyz, h, knn, bq_out, A + 98304, rhT, z_ws, qx_ws, out);
}